// Round 16
// baseline (562.724 us; speedup 1.0000x reference)
//
#include <hip/hip_runtime.h>
#include <hip/hip_bf16.h>

typedef unsigned short u16;
typedef unsigned int u32;
typedef __bf16 bf16x8 __attribute__((ext_vector_type(8)));
typedef float f32x4 __attribute__((ext_vector_type(4)));
typedef u16 u16x8 __attribute__((ext_vector_type(8)));
typedef u16 u16x4 __attribute__((ext_vector_type(4)));

#define NB 4
#define SEQ 2048
#define EMB 1024
#define NHEAD 16
#define DHEAD 64
#define MTOT (NB*SEQ)   // 8192

static __device__ __forceinline__ u16 f2bf(float f) {
  union { __bf16 h; u16 u; } cv;
  cv.h = (__bf16)f;
  return cv.u;
}

static __device__ __forceinline__ float fexp2(float x) {
  float r;
  asm("v_exp_f32 %0, %1" : "=v"(r) : "v"(x));   // exp2, 1 instr, exp2(-inf)=0
  return r;
}

static __device__ __forceinline__ void gload16(const void* g, void* l) {
  // async global->LDS, 16B per lane; dest = (wave-uniform l) + lane*16
  __builtin_amdgcn_global_load_lds((const __attribute__((address_space(1))) void*)g,
                                   (__attribute__((address_space(3))) void*)l, 16, 0, 0);
}

// ---------------- conversion kernels ----------------

__global__ __launch_bounds__(256) void k_cvt_x(const float* __restrict__ in, u16* __restrict__ out) {
  size_t i = (size_t)blockIdx.x * 256 + threadIdx.x;
  const float4* p = (const float4*)in + i * 2;
  float4 a = p[0], b = p[1];
  u16x8 r;
  r[0] = f2bf(a.x); r[1] = f2bf(a.y); r[2] = f2bf(a.z); r[3] = f2bf(a.w);
  r[4] = f2bf(b.x); r[5] = f2bf(b.y); r[6] = f2bf(b.z); r[7] = f2bf(b.w);
  *(u16x8*)(out + i * 8) = r;
}

__global__ __launch_bounds__(256) void k_wtrans(const float* __restrict__ W0, const float* __restrict__ W1,
                                                const float* __restrict__ W2, const float* __restrict__ W3,
                                                u16* __restrict__ O0, u16* __restrict__ O1,
                                                u16* __restrict__ O2, u16* __restrict__ O3) {
  __shared__ float tile[64][65];
  const float* W = blockIdx.z == 0 ? W0 : blockIdx.z == 1 ? W1 : blockIdx.z == 2 ? W2 : W3;
  u16* O       = blockIdx.z == 0 ? O0 : blockIdx.z == 1 ? O1 : blockIdx.z == 2 ? O2 : O3;
  const int c0 = blockIdx.x * 64, r0 = blockIdx.y * 64;
  const int t = threadIdx.x;
  const int tr = t >> 4, tc = (t & 15) * 4;
#pragma unroll
  for (int p = 0; p < 4; p++) {
    int r = tr + p * 16;
    float4 v = *(const float4*)&W[(size_t)(r0 + r) * EMB + c0 + tc];
    tile[r][tc + 0] = v.x; tile[r][tc + 1] = v.y; tile[r][tc + 2] = v.z; tile[r][tc + 3] = v.w;
  }
  __syncthreads();
#pragma unroll
  for (int p = 0; p < 4; p++) {
    int orow = tr + p * 16;
    u16x4 o;
    o[0] = f2bf(tile[tc + 0][orow]); o[1] = f2bf(tile[tc + 1][orow]);
    o[2] = f2bf(tile[tc + 2][orow]); o[3] = f2bf(tile[tc + 3][orow]);
    *(u16x4*)&O[(size_t)(c0 + orow) * EMB + r0 + tc] = o;
  }
}

// ---------------- GEMM core (128x128, 4 waves): used by gemm_out ----------------

static __device__ __forceinline__ void gemm_core(const u16* __restrict__ A, const u16* __restrict__ BT,
                                                 int m0, int n0, f32x4 acc[4][4]) {
  __shared__ u16 As[2][128 * 64];
  __shared__ u16 Bs[2][128 * 64];
  const int t = threadIdx.x, l = t & 63, w = t >> 6;
  const int g = l >> 4, q = l & 15;
  const int wm = (w >> 1) * 64, wn = (w & 1) * 64;

  const f32x4 zero4 = {0.f, 0.f, 0.f, 0.f};
#pragma unroll
  for (int mi = 0; mi < 4; mi++)
#pragma unroll
    for (int ni = 0; ni < 4; ni++) acc[mi][ni] = zero4;

  int srow[4], skel[4];
#pragma unroll
  for (int i = 0; i < 4; i++) {
    int row = w * 32 + i * 8 + (l >> 3);
    srow[i] = row; skel[i] = ((l & 7) ^ (row & 7)) * 8;
  }

  auto stage = [&](int k0, int bsel) {
    char* AsB = (char*)As[bsel] + w * 4096;
    char* BsB = (char*)Bs[bsel] + w * 4096;
#pragma unroll
    for (int i = 0; i < 4; i++) {
      gload16(A + (size_t)(m0 + srow[i]) * EMB + k0 + skel[i], AsB + i * 1024);
      gload16(BT + (size_t)(n0 + srow[i]) * EMB + k0 + skel[i], BsB + i * 1024);
    }
  };

  auto compute = [&](int bsel) {
    char* AsB = (char*)As[bsel];
    char* BsB = (char*)Bs[bsel];
#pragma unroll
    for (int kc = 0; kc < 2; kc++) {
      bf16x8 af[4], bfv[4];
#pragma unroll
      for (int mi = 0; mi < 4; mi++) {
        int row = wm + mi * 16 + q;
        af[mi] = *(const bf16x8*)(AsB + row * 128 + (((kc * 4 + g) ^ (row & 7)) << 4));
      }
#pragma unroll
      for (int ni = 0; ni < 4; ni++) {
        int row = wn + ni * 16 + q;
        bfv[ni] = *(const bf16x8*)(BsB + row * 128 + (((kc * 4 + g) ^ (row & 7)) << 4));
      }
      __builtin_amdgcn_s_setprio(1);
#pragma unroll
      for (int mi = 0; mi < 4; mi++)
#pragma unroll
        for (int ni = 0; ni < 4; ni++)
          acc[mi][ni] = __builtin_amdgcn_mfma_f32_16x16x32_bf16(af[mi], bfv[ni], acc[mi][ni], 0, 0, 0);
      __builtin_amdgcn_s_setprio(0);
    }
  };

  stage(0, 0);
  int buf = 0;
  for (int k0 = 64; k0 <= EMB; k0 += 64) {
    const bool pf = (k0 < EMB);
    if (pf) {
      stage(k0, buf ^ 1);
      asm volatile("s_waitcnt vmcnt(8)" ::: "memory");
    } else {
      asm volatile("s_waitcnt vmcnt(0)" ::: "memory");
    }
    __builtin_amdgcn_s_barrier();
    __builtin_amdgcn_sched_barrier(0);
    compute(buf);
    asm volatile("s_waitcnt lgkmcnt(0)" ::: "memory");
    __builtin_amdgcn_s_barrier();
    buf ^= 1;
  }
}

// ---------------- Fused QKV: 256x256 tile, 8 waves, 8-phase, BK=32 (2 blocks/CU) ----------------
// R16: BK 64->32 halves LDS (128->64 KB) -> 2 blocks/CU -> all 384 blocks co-resident,
// eliminating the half-empty second scheduling round (was 2 rounds at 1 block/CU).
// Same phase/staging/ledger structure as the verified R9 schedule, scaled:
//   1 gload16/thread per half-tile (128 rows x 32 k = 8 KB); 32 K-tiles; dbuf = tile&1.
//   phi0: stage A1(t+1); phi1: B0(t+1); phi2: A0(t+2); phi3: B1(t+2); vmcnt(2) at phi3.
// 64B-row swizzle: LDS position p of row w holds logical chunk (p + (w>>1)) & 3.
//   Read chunk g of row w at p = (g - (w>>1)) & 3 -> bank group (16*(w&1) + 4p)%32 takes
//   8 distinct values over 16 consecutive rows -> 2-way conflict = free (m136).
__global__ __launch_bounds__(512, 4) void k_gemm_qkv(const u16* __restrict__ xb, const u16* __restrict__ Wqkv,
                                                     u16* __restrict__ Qb, u16* __restrict__ Kb, u16* __restrict__ Vb) {
  __shared__ u16 As[2][256 * 32];   // 32 KB total  [dbuf][half*4096 + w*32 + k]
  __shared__ u16 Bs[2][256 * 32];   // 32 KB total
  const int t = threadIdx.x, l = t & 63, wid = t >> 6;
  const int g = l >> 4, q = l & 15;
  const int wr = wid >> 2, wc = wid & 3;        // 2 x 4 wave grid within quadrant

  const int wg = blockIdx.x;                    // 384 = 32 m x 12 n
  const int c = wg & 7, local = wg >> 3;        // XCD c gets n-outer chunk
  const int idx = c * 48 + local;
  const int ni_ = idx >> 5, mi_ = idx & 31;
  const int m0 = mi_ * 256, n0 = ni_ * 256;

  f32x4 acc[2][2][4][2];                        // [R][C][mi][ni]
  const f32x4 zero4 = {0.f, 0.f, 0.f, 0.f};
#pragma unroll
  for (int R = 0; R < 2; R++)
#pragma unroll
    for (int C = 0; C < 2; C++)
#pragma unroll
      for (int mi = 0; mi < 4; mi++)
#pragma unroll
        for (int ni = 0; ni < 2; ni++) acc[R][C][mi][ni] = zero4;

  // staging: thread t -> within-half row t>>2, chunk position t&3 (1 gload16/half-tile)
  const int srow = t >> 2;
  const int skel = (((t & 3) + (srow >> 1)) & 3) * 8;   // pre-swizzled source chunk

  auto stageHalf = [&](int op, int half, int tile) {
    if (tile >= 32) return;
    const int kk = tile * 32, d = tile & 1;
    const u16* src = op ? Wqkv : xb;
    const int base = op ? n0 : m0;
    char* dst = (char*)(op ? Bs[d] : As[d]) + half * 8192 + wid * 1024;
    gload16(src + (size_t)(base + half * 128 + srow) * EMB + kk + skel, dst);
  };

  bf16x8 af[4], bf0[2], bf1[2];
  auto loadA = [&](int R, int d) {
    char* Ab = (char*)As[d] + R * 8192;
#pragma unroll
    for (int mi = 0; mi < 4; mi++) {
      int w_ = wr * 64 + mi * 16 + q;          // within-half row
      af[mi] = *(const bf16x8*)(Ab + w_ * 64 + (((g - (w_ >> 1)) & 3) << 4));
    }
  };
  auto loadB = [&](int C, int d, bf16x8 (&bfv)[2]) {
    char* Bb = (char*)Bs[d] + C * 8192;
#pragma unroll
    for (int ni = 0; ni < 2; ni++) {
      int w_ = wc * 32 + ni * 16 + q;
      bfv[ni] = *(const bf16x8*)(Bb + w_ * 64 + (((g - (w_ >> 1)) & 3) << 4));
    }
  };

#define MFMA8(R, C, BF)                                                                    \
  do {                                                                                     \
    __builtin_amdgcn_s_setprio(1);                                                         \
    _Pragma("unroll")                                                                      \
    for (int mi = 0; mi < 4; mi++)                                                         \
      _Pragma("unroll")                                                                    \
      for (int ni = 0; ni < 2; ni++)                                                       \
        acc[R][C][mi][ni] = __builtin_amdgcn_mfma_f32_16x16x32_bf16(af[mi], BF[ni], acc[R][C][mi][ni], 0, 0, 0); \
    __builtin_amdgcn_s_setprio(0);                                                         \
  } while (0)

  // prologue: tile 0 fully + A0(1), B1(1) = 6 issues; keep newest 2 in flight
  stageHalf(0, 0, 0); stageHalf(1, 0, 0); stageHalf(1, 1, 0); stageHalf(0, 1, 0);
  stageHalf(0, 0, 1); stageHalf(1, 1, 1);
  asm volatile("s_waitcnt vmcnt(2)" ::: "memory");
  __builtin_amdgcn_s_barrier();
  __builtin_amdgcn_sched_barrier(0);

  for (int kt = 0; kt < 32; ++kt) {
    const int d = kt & 1;
    // phi0: quadrant (0,0)
    loadA(0, d); loadB(0, d, bf0);
    stageHalf(0, 1, kt + 1);                 // A1(kt+1)
    __builtin_amdgcn_s_barrier();
    MFMA8(0, 0, bf0);
    __builtin_amdgcn_s_barrier();
    __builtin_amdgcn_sched_barrier(0);
    // phi1: quadrant (0,1)
    loadB(1, d, bf1);
    stageHalf(1, 0, kt + 1);                 // B0(kt+1)
    __builtin_amdgcn_s_barrier();
    MFMA8(0, 1, bf1);
    __builtin_amdgcn_s_barrier();
    __builtin_amdgcn_sched_barrier(0);
    // phi2: quadrant (1,1)
    loadA(1, d);
    stageHalf(0, 0, kt + 2);                 // A0(kt+2)
    __builtin_amdgcn_s_barrier();
    MFMA8(1, 1, bf1);
    __builtin_amdgcn_s_barrier();
    __builtin_amdgcn_sched_barrier(0);
    // phi3: quadrant (1,0)
    stageHalf(1, 1, kt + 2);                 // B1(kt+2)
    __builtin_amdgcn_s_barrier();
    MFMA8(1, 0, bf0);
    if (kt <= 29)      asm volatile("s_waitcnt vmcnt(2)" ::: "memory");
    else if (kt == 30) asm volatile("s_waitcnt vmcnt(0)" ::: "memory");
    __builtin_amdgcn_s_barrier();
    __builtin_amdgcn_sched_barrier(0);
  }
#undef MFMA8

  const int z = n0 >> 10;
  u16* Out = z == 0 ? Qb : (z == 1 ? Kb : Vb);
  const float scale = z == 0 ? 0.125f * 1.4426950408889634f : 1.0f;

#pragma unroll
  for (int R = 0; R < 2; R++)
#pragma unroll
    for (int C = 0; C < 2; C++)
#pragma unroll
      for (int mi = 0; mi < 4; mi++)
#pragma unroll
        for (int ni = 0; ni < 2; ni++)
#pragma unroll
          for (int jj = 0; jj < 4; jj++) {
            int m = m0 + R * 128 + wr * 64 + mi * 16 + g * 4 + jj;
            int n = n0 + C * 128 + wc * 32 + ni * 16 + q;
            int b = m >> 11, s = m & 2047;
            int col = n & 1023;
            int h = col >> 6, dd = col & 63;
            Out[(((size_t)(b * NHEAD + h)) * SEQ + s) * DHEAD + dd] = f2bf(acc[R][C][mi][ni][jj] * scale);
          }
}

// Output projection: out(fp32) = Ob * Wo + bo. 512 = 64 m x 8 n; XCD c owns n-panel c.
__global__ __launch_bounds__(256) void k_gemm_out(const u16* __restrict__ Ob, const u16* __restrict__ WoT,
                                                  const float* __restrict__ bo, float* __restrict__ out) {
  const int wg = blockIdx.x;
  const int c = wg & 7, local = wg >> 3;
  const int m0 = (local & 63) * 128, n0 = c * 128;

  f32x4 acc[4][4];
  gemm_core(Ob, WoT, m0, n0, acc);

  const int t = threadIdx.x, l = t & 63, w = t >> 6;
  const int g = l >> 4, q = l & 15;
  const int wm = (w >> 1) * 64, wn = (w & 1) * 64;
#pragma unroll
  for (int ni = 0; ni < 4; ni++) {
    int n = n0 + wn + ni * 16 + q;
    float bv = bo[n];
#pragma unroll
    for (int mi = 0; mi < 4; mi++)
#pragma unroll
      for (int jj = 0; jj < 4; jj++) {
        int m = m0 + wm + mi * 16 + g * 4 + jj;
        out[(size_t)m * EMB + n] = acc[mi][ni][jj] + bv;
      }
  }
}

// ---------------- causal flash attention (merged-pair, zero-shuffle P, per-stream frags) ----------------
// R12 configuration (best measured, confirmed x3): q-tile pair (i, 31-i) per block, 4 waves,
// per-stream ds_reads, P in registers via sigma V layout, VALU-lean softmax, deferred l
// reduction, K/V double-buffered + prefetched. VGPR 64 / LDS 32KB / zero conflicts / zero spill.
__global__ __launch_bounds__(256, 4) void k_attn(const u16* __restrict__ Qb, const u16* __restrict__ Kb,
                                                 const u16* __restrict__ Vb, u16* __restrict__ Ob) {
  __shared__ u16 Ks[2][64 * 64];    // [key][d], swizzled 16B chunks, natural key order
  __shared__ u16 Vt[2][64 * 64];    // [d][slot], swizzled 16B chunks, sigma slot order
  const int t = threadIdx.x, l = t & 63, w = t >> 6;
  const int g = l >> 4, q = l & 15;
  const int bh = blockIdx.x;
  const int b = bh >> 4, h = bh & 15;
  const size_t hb = (size_t)bh * SEQ * DHEAD;
  const float NEG_INF = -__builtin_inff();

  const int i = blockIdx.y;
  const int qA0 = i * 64, qB0 = (31 - i) * 64;
  const int ntA = i + 1, ntB = 32 - i;

  int krow[2], kel[2];
#pragma unroll
  for (int ii = 0; ii < 2; ii++) {
    int row = w * 16 + ii * 8 + (l >> 3);
    krow[ii] = row; kel[ii] = ((l & 7) ^ (row & 7)) * 8;
  }
  const int kp = t & 31, d0v = (t >> 5) * 8;
  const int r2 = 2 * kp;
  const int sp = 32 * ((r2 >> 4) >> 1) + 8 * ((r2 >> 2) & 3) + 4 * ((r2 >> 4) & 1) + (r2 & 3);

  // precomputed LDS byte offsets (identical formula for K-frag and V-frag reads)
  int olds[2][4], owv[8];
#pragma unroll
  for (int kc = 0; kc < 2; kc++)
#pragma unroll
    for (int kf = 0; kf < 4; kf++) {
      int row = kf * 16 + q;
      olds[kc][kf] = row * 128 + (((kc * 4 + g) ^ (row & 7)) << 4);
    }
#pragma unroll
  for (int ii = 0; ii < 8; ii++) {
    int d = d0v + ii;
    owv[ii] = d * 128 + ((sp * 2) ^ ((d & 7) << 4));
  }

  // running global pointers (advance 64 rows x 64 d = 4096 elems per k-tile)
  const u16* kgp0 = Kb + hb + (size_t)krow[0] * DHEAD + kel[0];
  const u16* kgp1 = Kb + hb + (size_t)krow[1] * DHEAD + kel[1];
  const u16* vgp0 = Vb + hb + (size_t)(2 * kp) * DHEAD + d0v;
  const u16* vgp1 = vgp0 + DHEAD;

  auto stageK = [&](const u16* p0, const u16* p1, int bsel) {
    char* dst = (char*)Ks[bsel] + w * 2048;
    gload16(p0, dst);
    gload16(p1, dst + 1024);
  };
  auto writeV = [&](int bsel, const u16x8& v0, const u16x8& v1) {
    char* VtB = (char*)Vt[bsel];
#pragma unroll
    for (int ii = 0; ii < 8; ii++) {
      u32 val = (u32)v0[ii] | ((u32)v1[ii] << 16);
      *(u32*)(VtB + owv[ii]) = val;
    }
  };

  bf16x8 qfA[2], qfB[2];
#pragma unroll
  for (int kc = 0; kc < 2; kc++) {
    qfA[kc] = *(const bf16x8*)(Qb + hb + (size_t)(qA0 + w * 16 + q) * DHEAD + kc * 32 + g * 8);
    qfB[kc] = *(const bf16x8*)(Qb + hb + (size_t)(qB0 + w * 16 + q) * DHEAD + kc * 32 + g * 8);
  }
  const int qglobA = qA0 + w * 16 + q, qglobB = qB0 + w * 16 + q;

  f32x4 oA[4], oB[4];
  const f32x4 zero4 = {0.f, 0.f, 0.f, 0.f};
#pragma unroll
  for (int df = 0; df < 4; df++) { oA[df] = zero4; oB[df] = zero4; }
  float mA = NEG_INF, lA = 0.f, mB = NEG_INF, lB = 0.f;

  auto compute = [&](const bf16x8 (&qf)[2], f32x4 (&o)[4], float& m_run, float& l_run,
                     bool diag, int qglob, int k0, const char* KsB, const char* VtB) {
    f32x4 st[4];
#pragma unroll
    for (int kf = 0; kf < 4; kf++) st[kf] = zero4;
    __builtin_amdgcn_s_setprio(1);
#pragma unroll
    for (int kc = 0; kc < 2; kc++)
#pragma unroll
      for (int kf = 0; kf < 4; kf++) {
        bf16x8 a = *(const bf16x8*)(KsB + olds[kc][kf]);
        st[kf] = __builtin_amdgcn_mfma_f32_16x16x32_bf16(a, qf[kc], st[kf], 0, 0, 0);
      }
    __builtin_amdgcn_s_setprio(0);

    if (diag) {
#pragma unroll
      for (int kf = 0; kf < 4; kf++)
#pragma unroll
        for (int jj = 0; jj < 4; jj++)
          if (k0 + kf * 16 + g * 4 + jj > qglob) st[kf][jj] = NEG_INF;
    }

    // max3-friendly 16->1 tree (clang fuses fmaxf(fmaxf(a,b),c) -> v_max3_f32)
    float x0 = fmaxf(fmaxf(st[0][0], st[0][1]), st[0][2]);
    float x1 = fmaxf(fmaxf(st[0][3], st[1][0]), st[1][1]);
    float x2 = fmaxf(fmaxf(st[1][2], st[1][3]), st[2][0]);
    float x3 = fmaxf(fmaxf(st[2][1], st[2][2]), st[2][3]);
    float x4 = fmaxf(fmaxf(st[3][0], st[3][1]), st[3][2]);
    float smax = fmaxf(fmaxf(x0, x1), x2);
    smax = fmaxf(fmaxf(smax, x3), x4);
    smax = fmaxf(smax, st[3][3]);
    smax = fmaxf(smax, __shfl_xor(smax, 16));
    smax = fmaxf(smax, __shfl_xor(smax, 32));

    if (!__all(smax - m_run <= 8.0f)) {   // defer-max (log2 domain)
      float mnew = fmaxf(m_run, smax);
      float sc = fexp2(m_run - mnew);
      l_run *= sc;                        // per-lane partial scales identically
#pragma unroll
      for (int jj = 0; jj < 4; jj++) {
        float scj = __shfl(sc, g * 4 + jj);
#pragma unroll
        for (int df = 0; df < 4; df++) o[df][jj] *= scj;
      }
      m_run = mnew;
    }

    f32x4 pv[4];
#pragma unroll
    for (int kf = 0; kf < 4; kf++)
#pragma unroll
      for (int jj = 0; jj < 4; jj++)
        pv[kf][jj] = fexp2(st[kf][jj] - m_run);
    f32x4 sv = (pv[0] + pv[1]) + (pv[2] + pv[3]);
    l_run += (sv[0] + sv[1]) + (sv[2] + sv[3]);   // per-lane partial; reduced at epilogue

    bf16x8 pa[2];
    pa[0] = bf16x8{ (__bf16)pv[0][0], (__bf16)pv[0][1], (__bf16)pv[0][2], (__bf16)pv[0][3],
                    (__bf16)pv[1][0], (__bf16)pv[1][1], (__bf16)pv[1][2], (__bf16)pv[1][3] };
    pa[1] = bf16x8{ (__bf16)pv[2][0], (__bf16)pv[2][1], (__bf16)pv[2][2], (__bf16)pv[2][3],
                    (__bf16)pv[3][0], (__bf16)pv[3][1], (__bf16)pv[3][2], (__bf16)pv[3][3] };

    __builtin_amdgcn_s_setprio(1);
#pragma unroll
    for (int kc = 0; kc < 2; kc++)
#pragma unroll
      for (int df = 0; df < 4; df++) {
        bf16x8 vb = *(const bf16x8*)(VtB + olds[kc][df]);
        o[df] = __builtin_amdgcn_mfma_f32_16x16x32_bf16(pa[kc], vb, o[df], 0, 0, 0);
      }
    __builtin_amdgcn_s_setprio(0);
  };

  {  // prologue: stage tile 0
    u16x8 v0 = *(const u16x8*)vgp0, v1 = *(const u16x8*)vgp1;
    stageK(kgp0, kgp1, 0);
    writeV(0, v0, v1);
    kgp0 += 4096; kgp1 += 4096; vgp0 += 4096; vgp1 += 4096;
  }
  __syncthreads();

  int buf = 0;
  for (int kt = 0; kt < ntB; ++kt) {
    const int k0 = kt * 64;
    const bool pf = (kt + 1 < ntB);
    u16x8 nv0, nv1;
    if (pf) {
      stageK(kgp0, kgp1, buf ^ 1);
      nv0 = *(const u16x8*)vgp0; nv1 = *(const u16x8*)vgp1;
      kgp0 += 4096; kgp1 += 4096; vgp0 += 4096; vgp1 += 4096;
    }
    const char* KsB = (const char*)Ks[buf];
    const char* VtB = (const char*)Vt[buf];

    compute(qfB, oB, mB, lB, kt == ntB - 1, qglobB, k0, KsB, VtB);
    if (kt < ntA)
      compute(qfA, oA, mA, lA, kt == ntA - 1, qglobA, k0, KsB, VtB);

    if (pf) writeV(buf ^ 1, nv0, nv1);
    __syncthreads();
    buf ^= 1;
  }

  // epilogue: finish deferred l reduction, normalize, store (B,S,E) bf16
  lA += __shfl_xor(lA, 16); lA += __shfl_xor(lA, 32);
  lB += __shfl_xor(lB, 16); lB += __shfl_xor(lB, 32);

  auto store = [&](f32x4 (&o)[4], float l_run, int q0) {
    float inv = 1.f / l_run;
#pragma unroll
    for (int jj = 0; jj < 4; jj++) {
      float r = __shfl(inv, g * 4 + jj);
      int s = q0 + w * 16 + g * 4 + jj;
#pragma unroll
      for (int df = 0; df < 4; df++)
        Ob[((size_t)(b * SEQ + s)) * EMB + h * DHEAD + df * 16 + q] = f2bf(o[df][jj] * r);
    }
  };
  store(oA, lA, qA0);
  store(oB, lB, qB0);
}

// ---------------- host ----------------

extern "C" void kernel_launch(void* const* d_in, const int* in_sizes, int n_in,
                              void* d_out, int out_size, void* d_ws, size_t ws_size,
                              hipStream_t stream) {
  const float* x  = (const float*)d_in[0];
  const float* Wq = (const float*)d_in[1];
  const float* Wk = (const float*)d_in[2];
  const float* Wv = (const float*)d_in[3];
  const float* Wo = (const float*)d_in[4];
  const float* bo = (const float*)d_in[5];
  float* out = (float*)d_out;

  char* ws = (char*)d_ws;
  u16* xb  = (u16*)(ws);                                   // 16 MB
  u16* WqT = (u16*)(ws + (16u << 20));                     // 2 MB each; Wq/Wk/Wv contiguous = fused B
  u16* WkT = WqT + (size_t)EMB * EMB;
  u16* WvT = WkT + (size_t)EMB * EMB;
  u16* WoT = WvT + (size_t)EMB * EMB;
  u16* Qb  = (u16*)(ws + (24u << 20));                     // 16 MB each
  u16* Kb  = Qb + (size_t)MTOT * EMB;
  u16* Vb  = Kb + (size_t)MTOT * EMB;
  u16* Ob  = Vb + (size_t)MTOT * EMB;                      // total 88 MB

  k_cvt_x<<<dim3(4096), 256, 0, stream>>>(x, xb);
  k_wtrans<<<dim3(16, 16, 4), 256, 0, stream>>>(Wq, Wk, Wv, Wo, WqT, WkT, WvT, WoT);
  k_gemm_qkv<<<dim3(384), 512, 0, stream>>>(xb, WqT, Qb, Kb, Vb);
  k_attn<<<dim3(64, 16), 256, 0, stream>>>(Qb, Kb, Vb, Ob);
  k_gemm_out<<<dim3(512), 256, 0, stream>>>(Ob, WoT, bo, out);
}

// Round 17
// 166.110 us; speedup vs baseline: 3.3877x; 3.3877x over previous
//
#include <hip/hip_runtime.h>
#include <hip/hip_bf16.h>

typedef unsigned short u16;
typedef unsigned int u32;
typedef __bf16 bf16x8 __attribute__((ext_vector_type(8)));
typedef float f32x4 __attribute__((ext_vector_type(4)));
typedef u16 u16x8 __attribute__((ext_vector_type(8)));
typedef u16 u16x4 __attribute__((ext_vector_type(4)));

#define NB 4
#define SEQ 2048
#define EMB 1024
#define NHEAD 16
#define DHEAD 64
#define MTOT (NB*SEQ)   // 8192

static __device__ __forceinline__ u16 f2bf(float f) {
  union { __bf16 h; u16 u; } cv;
  cv.h = (__bf16)f;
  return cv.u;
}

static __device__ __forceinline__ float fexp2(float x) {
  float r;
  asm("v_exp_f32 %0, %1" : "=v"(r) : "v"(x));   // exp2, 1 instr, exp2(-inf)=0
  return r;
}

static __device__ __forceinline__ void gload16(const void* g, void* l) {
  // async global->LDS, 16B per lane; dest = (wave-uniform l) + lane*16
  __builtin_amdgcn_global_load_lds((const __attribute__((address_space(1))) void*)g,
                                   (__attribute__((address_space(3))) void*)l, 16, 0, 0);
}

// ---------------- conversion kernels ----------------

__global__ __launch_bounds__(256) void k_cvt_x(const float* __restrict__ in, u16* __restrict__ out) {
  size_t i = (size_t)blockIdx.x * 256 + threadIdx.x;
  const float4* p = (const float4*)in + i * 2;
  float4 a = p[0], b = p[1];
  u16x8 r;
  r[0] = f2bf(a.x); r[1] = f2bf(a.y); r[2] = f2bf(a.z); r[3] = f2bf(a.w);
  r[4] = f2bf(b.x); r[5] = f2bf(b.y); r[6] = f2bf(b.z); r[7] = f2bf(b.w);
  *(u16x8*)(out + i * 8) = r;
}

__global__ __launch_bounds__(256) void k_wtrans(const float* __restrict__ W0, const float* __restrict__ W1,
                                                const float* __restrict__ W2, const float* __restrict__ W3,
                                                u16* __restrict__ O0, u16* __restrict__ O1,
                                                u16* __restrict__ O2, u16* __restrict__ O3) {
  __shared__ float tile[64][65];
  const float* W = blockIdx.z == 0 ? W0 : blockIdx.z == 1 ? W1 : blockIdx.z == 2 ? W2 : W3;
  u16* O       = blockIdx.z == 0 ? O0 : blockIdx.z == 1 ? O1 : blockIdx.z == 2 ? O2 : O3;
  const int c0 = blockIdx.x * 64, r0 = blockIdx.y * 64;
  const int t = threadIdx.x;
  const int tr = t >> 4, tc = (t & 15) * 4;
#pragma unroll
  for (int p = 0; p < 4; p++) {
    int r = tr + p * 16;
    float4 v = *(const float4*)&W[(size_t)(r0 + r) * EMB + c0 + tc];
    tile[r][tc + 0] = v.x; tile[r][tc + 1] = v.y; tile[r][tc + 2] = v.z; tile[r][tc + 3] = v.w;
  }
  __syncthreads();
#pragma unroll
  for (int p = 0; p < 4; p++) {
    int orow = tr + p * 16;
    u16x4 o;
    o[0] = f2bf(tile[tc + 0][orow]); o[1] = f2bf(tile[tc + 1][orow]);
    o[2] = f2bf(tile[tc + 2][orow]); o[3] = f2bf(tile[tc + 3][orow]);
    *(u16x4*)&O[(size_t)(c0 + orow) * EMB + r0 + tc] = o;
  }
}

// ---------------- GEMM core (128x128, 4 waves): used by gemm_out ----------------

static __device__ __forceinline__ void gemm_core(const u16* __restrict__ A, const u16* __restrict__ BT,
                                                 int m0, int n0, f32x4 acc[4][4]) {
  __shared__ u16 As[2][128 * 64];
  __shared__ u16 Bs[2][128 * 64];
  const int t = threadIdx.x, l = t & 63, w = t >> 6;
  const int g = l >> 4, q = l & 15;
  const int wm = (w >> 1) * 64, wn = (w & 1) * 64;

  const f32x4 zero4 = {0.f, 0.f, 0.f, 0.f};
#pragma unroll
  for (int mi = 0; mi < 4; mi++)
#pragma unroll
    for (int ni = 0; ni < 4; ni++) acc[mi][ni] = zero4;

  int srow[4], skel[4];
#pragma unroll
  for (int i = 0; i < 4; i++) {
    int row = w * 32 + i * 8 + (l >> 3);
    srow[i] = row; skel[i] = ((l & 7) ^ (row & 7)) * 8;
  }

  auto stage = [&](int k0, int bsel) {
    char* AsB = (char*)As[bsel] + w * 4096;
    char* BsB = (char*)Bs[bsel] + w * 4096;
#pragma unroll
    for (int i = 0; i < 4; i++) {
      gload16(A + (size_t)(m0 + srow[i]) * EMB + k0 + skel[i], AsB + i * 1024);
      gload16(BT + (size_t)(n0 + srow[i]) * EMB + k0 + skel[i], BsB + i * 1024);
    }
  };

  auto compute = [&](int bsel) {
    char* AsB = (char*)As[bsel];
    char* BsB = (char*)Bs[bsel];
#pragma unroll
    for (int kc = 0; kc < 2; kc++) {
      bf16x8 af[4], bfv[4];
#pragma unroll
      for (int mi = 0; mi < 4; mi++) {
        int row = wm + mi * 16 + q;
        af[mi] = *(const bf16x8*)(AsB + row * 128 + (((kc * 4 + g) ^ (row & 7)) << 4));
      }
#pragma unroll
      for (int ni = 0; ni < 4; ni++) {
        int row = wn + ni * 16 + q;
        bfv[ni] = *(const bf16x8*)(BsB + row * 128 + (((kc * 4 + g) ^ (row & 7)) << 4));
      }
      __builtin_amdgcn_s_setprio(1);
#pragma unroll
      for (int mi = 0; mi < 4; mi++)
#pragma unroll
        for (int ni = 0; ni < 4; ni++)
          acc[mi][ni] = __builtin_amdgcn_mfma_f32_16x16x32_bf16(af[mi], bfv[ni], acc[mi][ni], 0, 0, 0);
      __builtin_amdgcn_s_setprio(0);
    }
  };

  stage(0, 0);
  int buf = 0;
  for (int k0 = 64; k0 <= EMB; k0 += 64) {
    const bool pf = (k0 < EMB);
    if (pf) {
      stage(k0, buf ^ 1);
      asm volatile("s_waitcnt vmcnt(8)" ::: "memory");
    } else {
      asm volatile("s_waitcnt vmcnt(0)" ::: "memory");
    }
    __builtin_amdgcn_s_barrier();
    __builtin_amdgcn_sched_barrier(0);
    compute(buf);
    asm volatile("s_waitcnt lgkmcnt(0)" ::: "memory");
    __builtin_amdgcn_s_barrier();
    buf ^= 1;
  }
}

// ---------------- Fused QKV: 256x256 tile, 8 waves, 8-phase schedule ----------------
__global__ __launch_bounds__(512, 2) void k_gemm_qkv(const u16* __restrict__ xb, const u16* __restrict__ Wqkv,
                                                     u16* __restrict__ Qb, u16* __restrict__ Kb, u16* __restrict__ Vb) {
  __shared__ u16 As[2][256 * 64];   // 64 KB  [dbuf][row][k], rows 0-127 = half0, 128-255 = half1
  __shared__ u16 Bs[2][256 * 64];   // 64 KB
  const int t = threadIdx.x, l = t & 63, wid = t >> 6;
  const int g = l >> 4, q = l & 15;
  const int wr = wid >> 2, wc = wid & 3;        // 2 x 4 wave grid within quadrant

  const int wg = blockIdx.x;                    // 384 = 32 m x 12 n
  const int c = wg & 7, local = wg >> 3;        // XCD c gets n-outer chunk
  const int idx = c * 48 + local;
  const int ni_ = idx >> 5, mi_ = idx & 31;
  const int m0 = mi_ * 256, n0 = ni_ * 256;

  f32x4 acc[2][2][4][2];                        // [R][C][mi][ni]
  const f32x4 zero4 = {0.f, 0.f, 0.f, 0.f};
#pragma unroll
  for (int R = 0; R < 2; R++)
#pragma unroll
    for (int C = 0; C < 2; C++)
#pragma unroll
      for (int mi = 0; mi < 4; mi++)
#pragma unroll
        for (int ni = 0; ni < 2; ni++) acc[R][C][mi][ni] = zero4;

  int srow[2], skel[2];
#pragma unroll
  for (int j = 0; j < 2; j++) {
    int row = j * 64 + (t >> 3);
    srow[j] = row; skel[j] = ((t & 7) ^ (row & 7)) * 8;
  }

  auto stageHalf = [&](int op, int half, int tile) {
    if (tile >= 16) return;
    const int kk = tile * 64, d = tile & 1;
    const u16* src = op ? Wqkv : xb;
    const int base = op ? n0 : m0;
    char* dst = (char*)(op ? Bs[d] : As[d]) + half * 16384 + wid * 1024;
#pragma unroll
    for (int j = 0; j < 2; j++)
      gload16(src + (size_t)(base + half * 128 + srow[j]) * EMB + kk + skel[j], dst + j * 8192);
  };

  bf16x8 af[4][2], bf0[2][2], bf1[2][2];
  auto loadA = [&](int R, int d) {
    char* Ab = (char*)As[d];
#pragma unroll
    for (int mi = 0; mi < 4; mi++)
#pragma unroll
      for (int kc = 0; kc < 2; kc++) {
        int row = R * 128 + wr * 64 + mi * 16 + q;
        af[mi][kc] = *(const bf16x8*)(Ab + row * 128 + (((kc * 4 + g) ^ (row & 7)) << 4));
      }
  };
  auto loadB = [&](int C, int d, bf16x8 (&bfv)[2][2]) {
    char* Bb = (char*)Bs[d];
#pragma unroll
    for (int ni = 0; ni < 2; ni++)
#pragma unroll
      for (int kc = 0; kc < 2; kc++) {
        int row = C * 128 + wc * 32 + ni * 16 + q;
        bfv[ni][kc] = *(const bf16x8*)(Bb + row * 128 + (((kc * 4 + g) ^ (row & 7)) << 4));
      }
  };

#define MFMA16(R, C, BF)                                                                   \
  do {                                                                                     \
    __builtin_amdgcn_s_setprio(1);                                                         \
    _Pragma("unroll")                                                                      \
    for (int kc = 0; kc < 2; kc++)                                                         \
      _Pragma("unroll")                                                                    \
      for (int mi = 0; mi < 4; mi++)                                                       \
        _Pragma("unroll")                                                                  \
        for (int ni = 0; ni < 2; ni++)                                                     \
          acc[R][C][mi][ni] = __builtin_amdgcn_mfma_f32_16x16x32_bf16(af[mi][kc], BF[ni][kc], acc[R][C][mi][ni], 0, 0, 0); \
    __builtin_amdgcn_s_setprio(0);                                                         \
  } while (0)

  stageHalf(0, 0, 0); stageHalf(1, 0, 0); stageHalf(1, 1, 0); stageHalf(0, 1, 0);
  stageHalf(0, 0, 1); stageHalf(1, 1, 1);
  asm volatile("s_waitcnt vmcnt(4)" ::: "memory");
  __builtin_amdgcn_s_barrier();
  __builtin_amdgcn_sched_barrier(0);

  for (int kt = 0; kt < 16; ++kt) {
    const int d = kt & 1;
    loadA(0, d); loadB(0, d, bf0);
    stageHalf(0, 1, kt + 1);                 // A1(kt+1)
    __builtin_amdgcn_s_barrier();
    MFMA16(0, 0, bf0);
    __builtin_amdgcn_s_barrier();
    __builtin_amdgcn_sched_barrier(0);
    loadB(1, d, bf1);
    stageHalf(1, 0, kt + 1);                 // B0(kt+1)
    __builtin_amdgcn_s_barrier();
    MFMA16(0, 1, bf1);
    __builtin_amdgcn_s_barrier();
    __builtin_amdgcn_sched_barrier(0);
    loadA(1, d);
    stageHalf(0, 0, kt + 2);                 // A0(kt+2)
    __builtin_amdgcn_s_barrier();
    MFMA16(1, 1, bf1);
    __builtin_amdgcn_s_barrier();
    __builtin_amdgcn_sched_barrier(0);
    stageHalf(1, 1, kt + 2);                 // B1(kt+2)
    __builtin_amdgcn_s_barrier();
    MFMA16(1, 0, bf0);
    if (kt <= 13)      asm volatile("s_waitcnt vmcnt(4)" ::: "memory");
    else if (kt == 14) asm volatile("s_waitcnt vmcnt(0)" ::: "memory");
    __builtin_amdgcn_s_barrier();
    __builtin_amdgcn_sched_barrier(0);
  }
#undef MFMA16

  const int z = n0 >> 10;
  u16* Out = z == 0 ? Qb : (z == 1 ? Kb : Vb);
  const float scale = z == 0 ? 0.125f * 1.4426950408889634f : 1.0f;

#pragma unroll
  for (int R = 0; R < 2; R++)
#pragma unroll
    for (int C = 0; C < 2; C++)
#pragma unroll
      for (int mi = 0; mi < 4; mi++)
#pragma unroll
        for (int ni = 0; ni < 2; ni++)
#pragma unroll
          for (int jj = 0; jj < 4; jj++) {
            int m = m0 + R * 128 + wr * 64 + mi * 16 + g * 4 + jj;
            int n = n0 + C * 128 + wc * 32 + ni * 16 + q;
            int b = m >> 11, s = m & 2047;
            int col = n & 1023;
            int h = col >> 6, dd = col & 63;
            Out[(((size_t)(b * NHEAD + h)) * SEQ + s) * DHEAD + dd] = f2bf(acc[R][C][mi][ni][jj] * scale);
          }
}

// Output projection: out(fp32) = Ob * Wo + bo. 512 = 64 m x 8 n; XCD c owns n-panel c.
__global__ __launch_bounds__(256) void k_gemm_out(const u16* __restrict__ Ob, const u16* __restrict__ WoT,
                                                  const float* __restrict__ bo, float* __restrict__ out) {
  const int wg = blockIdx.x;
  const int c = wg & 7, local = wg >> 3;
  const int m0 = (local & 63) * 128, n0 = c * 128;

  f32x4 acc[4][4];
  gemm_core(Ob, WoT, m0, n0, acc);

  const int t = threadIdx.x, l = t & 63, w = t >> 6;
  const int g = l >> 4, q = l & 15;
  const int wm = (w >> 1) * 64, wn = (w & 1) * 64;
#pragma unroll
  for (int ni = 0; ni < 4; ni++) {
    int n = n0 + wn + ni * 16 + q;
    float bv = bo[n];
#pragma unroll
    for (int mi = 0; mi < 4; mi++)
#pragma unroll
      for (int jj = 0; jj < 4; jj++) {
        int m = m0 + wm + mi * 16 + g * 4 + jj;
        out[(size_t)m * EMB + n] = acc[mi][ni][jj] + bv;
      }
  }
}

// ---------------- causal flash attention (merged-pair, zero-shuffle P, per-stream frags) ----------------
// R12 configuration (best measured, confirmed x3): q-tile pair (i, 31-i) per block, 4 waves,
// per-stream ds_reads, P in registers via sigma V layout, VALU-lean softmax, deferred l
// reduction, K/V double-buffered + prefetched. VGPR 64 / LDS 32KB / zero conflicts / zero spill.
__global__ __launch_bounds__(256, 4) void k_attn(const u16* __restrict__ Qb, const u16* __restrict__ Kb,
                                                 const u16* __restrict__ Vb, u16* __restrict__ Ob) {
  __shared__ u16 Ks[2][64 * 64];    // [key][d], swizzled 16B chunks, natural key order
  __shared__ u16 Vt[2][64 * 64];    // [d][slot], swizzled 16B chunks, sigma slot order
  const int t = threadIdx.x, l = t & 63, w = t >> 6;
  const int g = l >> 4, q = l & 15;
  const int bh = blockIdx.x;
  const int b = bh >> 4, h = bh & 15;
  const size_t hb = (size_t)bh * SEQ * DHEAD;
  const float NEG_INF = -__builtin_inff();

  const int i = blockIdx.y;
  const int qA0 = i * 64, qB0 = (31 - i) * 64;
  const int ntA = i + 1, ntB = 32 - i;

  int krow[2], kel[2];
#pragma unroll
  for (int ii = 0; ii < 2; ii++) {
    int row = w * 16 + ii * 8 + (l >> 3);
    krow[ii] = row; kel[ii] = ((l & 7) ^ (row & 7)) * 8;
  }
  const int kp = t & 31, d0v = (t >> 5) * 8;
  const int r2 = 2 * kp;
  const int sp = 32 * ((r2 >> 4) >> 1) + 8 * ((r2 >> 2) & 3) + 4 * ((r2 >> 4) & 1) + (r2 & 3);

  // precomputed LDS byte offsets (identical formula for K-frag and V-frag reads)
  int olds[2][4], owv[8];
#pragma unroll
  for (int kc = 0; kc < 2; kc++)
#pragma unroll
    for (int kf = 0; kf < 4; kf++) {
      int row = kf * 16 + q;
      olds[kc][kf] = row * 128 + (((kc * 4 + g) ^ (row & 7)) << 4);
    }
#pragma unroll
  for (int ii = 0; ii < 8; ii++) {
    int d = d0v + ii;
    owv[ii] = d * 128 + ((sp * 2) ^ ((d & 7) << 4));
  }

  // running global pointers (advance 64 rows x 64 d = 4096 elems per k-tile)
  const u16* kgp0 = Kb + hb + (size_t)krow[0] * DHEAD + kel[0];
  const u16* kgp1 = Kb + hb + (size_t)krow[1] * DHEAD + kel[1];
  const u16* vgp0 = Vb + hb + (size_t)(2 * kp) * DHEAD + d0v;
  const u16* vgp1 = vgp0 + DHEAD;

  auto stageK = [&](const u16* p0, const u16* p1, int bsel) {
    char* dst = (char*)Ks[bsel] + w * 2048;
    gload16(p0, dst);
    gload16(p1, dst + 1024);
  };
  auto writeV = [&](int bsel, const u16x8& v0, const u16x8& v1) {
    char* VtB = (char*)Vt[bsel];
#pragma unroll
    for (int ii = 0; ii < 8; ii++) {
      u32 val = (u32)v0[ii] | ((u32)v1[ii] << 16);
      *(u32*)(VtB + owv[ii]) = val;
    }
  };

  bf16x8 qfA[2], qfB[2];
#pragma unroll
  for (int kc = 0; kc < 2; kc++) {
    qfA[kc] = *(const bf16x8*)(Qb + hb + (size_t)(qA0 + w * 16 + q) * DHEAD + kc * 32 + g * 8);
    qfB[kc] = *(const bf16x8*)(Qb + hb + (size_t)(qB0 + w * 16 + q) * DHEAD + kc * 32 + g * 8);
  }
  const int qglobA = qA0 + w * 16 + q, qglobB = qB0 + w * 16 + q;

  f32x4 oA[4], oB[4];
  const f32x4 zero4 = {0.f, 0.f, 0.f, 0.f};
#pragma unroll
  for (int df = 0; df < 4; df++) { oA[df] = zero4; oB[df] = zero4; }
  float mA = NEG_INF, lA = 0.f, mB = NEG_INF, lB = 0.f;

  auto compute = [&](const bf16x8 (&qf)[2], f32x4 (&o)[4], float& m_run, float& l_run,
                     bool diag, int qglob, int k0, const char* KsB, const char* VtB) {
    f32x4 st[4];
#pragma unroll
    for (int kf = 0; kf < 4; kf++) st[kf] = zero4;
    __builtin_amdgcn_s_setprio(1);
#pragma unroll
    for (int kc = 0; kc < 2; kc++)
#pragma unroll
      for (int kf = 0; kf < 4; kf++) {
        bf16x8 a = *(const bf16x8*)(KsB + olds[kc][kf]);
        st[kf] = __builtin_amdgcn_mfma_f32_16x16x32_bf16(a, qf[kc], st[kf], 0, 0, 0);
      }
    __builtin_amdgcn_s_setprio(0);

    if (diag) {
#pragma unroll
      for (int kf = 0; kf < 4; kf++)
#pragma unroll
        for (int jj = 0; jj < 4; jj++)
          if (k0 + kf * 16 + g * 4 + jj > qglob) st[kf][jj] = NEG_INF;
    }

    // max3-friendly 16->1 tree (clang fuses fmaxf(fmaxf(a,b),c) -> v_max3_f32)
    float x0 = fmaxf(fmaxf(st[0][0], st[0][1]), st[0][2]);
    float x1 = fmaxf(fmaxf(st[0][3], st[1][0]), st[1][1]);
    float x2 = fmaxf(fmaxf(st[1][2], st[1][3]), st[2][0]);
    float x3 = fmaxf(fmaxf(st[2][1], st[2][2]), st[2][3]);
    float x4 = fmaxf(fmaxf(st[3][0], st[3][1]), st[3][2]);
    float smax = fmaxf(fmaxf(x0, x1), x2);
    smax = fmaxf(fmaxf(smax, x3), x4);
    smax = fmaxf(smax, st[3][3]);
    smax = fmaxf(smax, __shfl_xor(smax, 16));
    smax = fmaxf(smax, __shfl_xor(smax, 32));

    if (!__all(smax - m_run <= 8.0f)) {   // defer-max (log2 domain)
      float mnew = fmaxf(m_run, smax);
      float sc = fexp2(m_run - mnew);
      l_run *= sc;                        // per-lane partial scales identically
#pragma unroll
      for (int jj = 0; jj < 4; jj++) {
        float scj = __shfl(sc, g * 4 + jj);
#pragma unroll
        for (int df = 0; df < 4; df++) o[df][jj] *= scj;
      }
      m_run = mnew;
    }

    f32x4 pv[4];
#pragma unroll
    for (int kf = 0; kf < 4; kf++)
#pragma unroll
      for (int jj = 0; jj < 4; jj++)
        pv[kf][jj] = fexp2(st[kf][jj] - m_run);
    f32x4 sv = (pv[0] + pv[1]) + (pv[2] + pv[3]);
    l_run += (sv[0] + sv[1]) + (sv[2] + sv[3]);   // per-lane partial; reduced at epilogue

    bf16x8 pa[2];
    pa[0] = bf16x8{ (__bf16)pv[0][0], (__bf16)pv[0][1], (__bf16)pv[0][2], (__bf16)pv[0][3],
                    (__bf16)pv[1][0], (__bf16)pv[1][1], (__bf16)pv[1][2], (__bf16)pv[1][3] };
    pa[1] = bf16x8{ (__bf16)pv[2][0], (__bf16)pv[2][1], (__bf16)pv[2][2], (__bf16)pv[2][3],
                    (__bf16)pv[3][0], (__bf16)pv[3][1], (__bf16)pv[3][2], (__bf16)pv[3][3] };

    __builtin_amdgcn_s_setprio(1);
#pragma unroll
    for (int kc = 0; kc < 2; kc++)
#pragma unroll
      for (int df = 0; df < 4; df++) {
        bf16x8 vb = *(const bf16x8*)(VtB + olds[kc][df]);
        o[df] = __builtin_amdgcn_mfma_f32_16x16x32_bf16(pa[kc], vb, o[df], 0, 0, 0);
      }
    __builtin_amdgcn_s_setprio(0);
  };

  {  // prologue: stage tile 0
    u16x8 v0 = *(const u16x8*)vgp0, v1 = *(const u16x8*)vgp1;
    stageK(kgp0, kgp1, 0);
    writeV(0, v0, v1);
    kgp0 += 4096; kgp1 += 4096; vgp0 += 4096; vgp1 += 4096;
  }
  __syncthreads();

  int buf = 0;
  for (int kt = 0; kt < ntB; ++kt) {
    const int k0 = kt * 64;
    const bool pf = (kt + 1 < ntB);
    u16x8 nv0, nv1;
    if (pf) {
      stageK(kgp0, kgp1, buf ^ 1);
      nv0 = *(const u16x8*)vgp0; nv1 = *(const u16x8*)vgp1;
      kgp0 += 4096; kgp1 += 4096; vgp0 += 4096; vgp1 += 4096;
    }
    const char* KsB = (const char*)Ks[buf];
    const char* VtB = (const char*)Vt[buf];

    compute(qfB, oB, mB, lB, kt == ntB - 1, qglobB, k0, KsB, VtB);
    if (kt < ntA)
      compute(qfA, oA, mA, lA, kt == ntA - 1, qglobA, k0, KsB, VtB);

    if (pf) writeV(buf ^ 1, nv0, nv1);
    __syncthreads();
    buf ^= 1;
  }

  // epilogue: finish deferred l reduction, normalize, store (B,S,E) bf16
  lA += __shfl_xor(lA, 16); lA += __shfl_xor(lA, 32);
  lB += __shfl_xor(lB, 16); lB += __shfl_xor(lB, 32);

  auto store = [&](f32x4 (&o)[4], float l_run, int q0) {
    float inv = 1.f / l_run;
#pragma unroll
    for (int jj = 0; jj < 4; jj++) {
      float r = __shfl(inv, g * 4 + jj);
      int s = q0 + w * 16 + g * 4 + jj;
#pragma unroll
      for (int df = 0; df < 4; df++)
        Ob[((size_t)(b * SEQ + s)) * EMB + h * DHEAD + df * 16 + q] = f2bf(o[df][jj] * r);
    }
  };
  store(oA, lA, qA0);
  store(oB, lB, qB0);
}

// ---------------- host ----------------

extern "C" void kernel_launch(void* const* d_in, const int* in_sizes, int n_in,
                              void* d_out, int out_size, void* d_ws, size_t ws_size,
                              hipStream_t stream) {
  const float* x  = (const float*)d_in[0];
  const float* Wq = (const float*)d_in[1];
  const float* Wk = (const float*)d_in[2];
  const float* Wv = (const float*)d_in[3];
  const float* Wo = (const float*)d_in[4];
  const float* bo = (const float*)d_in[5];
  float* out = (float*)d_out;

  char* ws = (char*)d_ws;
  u16* xb  = (u16*)(ws);                                   // 16 MB
  u16* WqT = (u16*)(ws + (16u << 20));                     // 2 MB each; Wq/Wk/Wv contiguous = fused B
  u16* WkT = WqT + (size_t)EMB * EMB;
  u16* WvT = WkT + (size_t)EMB * EMB;
  u16* WoT = WvT + (size_t)EMB * EMB;
  u16* Qb  = (u16*)(ws + (24u << 20));                     // 16 MB each
  u16* Kb  = Qb + (size_t)MTOT * EMB;
  u16* Vb  = Kb + (size_t)MTOT * EMB;
  u16* Ob  = Vb + (size_t)MTOT * EMB;                      // total 88 MB

  k_cvt_x<<<dim3(4096), 256, 0, stream>>>(x, xb);
  k_wtrans<<<dim3(16, 16, 4), 256, 0, stream>>>(Wq, Wk, Wv, Wo, WqT, WkT, WvT, WoT);
  k_gemm_qkv<<<dim3(384), 512, 0, stream>>>(xb, WqT, Qb, Kb, Vb);
  k_attn<<<dim3(64, 16), 256, 0, stream>>>(Qb, Kb, Vb, Ob);
  k_gemm_out<<<dim3(512), 256, 0, stream>>>(Ob, WoT, bo, out);
}

// Round 18
// 164.453 us; speedup vs baseline: 3.4218x; 1.0101x over previous
//
#include <hip/hip_runtime.h>
#include <hip/hip_bf16.h>

typedef unsigned short u16;
typedef unsigned int u32;
typedef __bf16 bf16x8 __attribute__((ext_vector_type(8)));
typedef float f32x4 __attribute__((ext_vector_type(4)));
typedef u16 u16x8 __attribute__((ext_vector_type(8)));
typedef u16 u16x4 __attribute__((ext_vector_type(4)));

#define NB 4
#define SEQ 2048
#define EMB 1024
#define NHEAD 16
#define DHEAD 64
#define MTOT (NB*SEQ)   // 8192

static __device__ __forceinline__ u16 f2bf(float f) {
  union { __bf16 h; u16 u; } cv;
  cv.h = (__bf16)f;
  return cv.u;
}

static __device__ __forceinline__ float fexp2(float x) {
  float r;
  asm("v_exp_f32 %0, %1" : "=v"(r) : "v"(x));   // exp2, 1 instr, exp2(-inf)=0
  return r;
}

static __device__ __forceinline__ void gload16(const void* g, void* l) {
  // async global->LDS, 16B per lane; dest = (wave-uniform l) + lane*16
  __builtin_amdgcn_global_load_lds((const __attribute__((address_space(1))) void*)g,
                                   (__attribute__((address_space(3))) void*)l, 16, 0, 0);
}

// ---------------- merged preprocessing: x->bf16 + 4x weight transpose->bf16 ----------------
// blocks [0,4096): cvt_x (8 elems/thread); blocks [4096,5120): wtrans decoded (16x16x4).
// The two populations are independent and memory-bound; one dispatch lets them co-schedule.
__global__ __launch_bounds__(256) void k_prep(const float* __restrict__ xin, u16* __restrict__ xb,
                                              const float* __restrict__ W0, const float* __restrict__ W1,
                                              const float* __restrict__ W2, const float* __restrict__ W3,
                                              u16* __restrict__ O0, u16* __restrict__ O1,
                                              u16* __restrict__ O2, u16* __restrict__ O3) {
  __shared__ float tile[64][65];
  const int bid = blockIdx.x;
  const int t = threadIdx.x;

  if (bid < 4096) {   // ---- cvt_x ----
    size_t i = (size_t)bid * 256 + t;
    const float4* p = (const float4*)xin + i * 2;
    float4 a = p[0], b = p[1];
    u16x8 r;
    r[0] = f2bf(a.x); r[1] = f2bf(a.y); r[2] = f2bf(a.z); r[3] = f2bf(a.w);
    r[4] = f2bf(b.x); r[5] = f2bf(b.y); r[6] = f2bf(b.z); r[7] = f2bf(b.w);
    *(u16x8*)(xb + i * 8) = r;
    return;
  }

  // ---- wtrans ----
  const int wb = bid - 4096;                   // 1024 blocks = 16 x 16 x 4
  const int z = wb >> 8, rem = wb & 255;
  const int by = rem >> 4, bx = rem & 15;
  const float* W = z == 0 ? W0 : z == 1 ? W1 : z == 2 ? W2 : W3;
  u16* O       = z == 0 ? O0 : z == 1 ? O1 : z == 2 ? O2 : O3;
  const int c0 = bx * 64, r0 = by * 64;
  const int tr = t >> 4, tc = (t & 15) * 4;
#pragma unroll
  for (int p = 0; p < 4; p++) {
    int r = tr + p * 16;
    float4 v = *(const float4*)&W[(size_t)(r0 + r) * EMB + c0 + tc];
    tile[r][tc + 0] = v.x; tile[r][tc + 1] = v.y; tile[r][tc + 2] = v.z; tile[r][tc + 3] = v.w;
  }
  __syncthreads();
#pragma unroll
  for (int p = 0; p < 4; p++) {
    int orow = tr + p * 16;
    u16x4 o;
    o[0] = f2bf(tile[tc + 0][orow]); o[1] = f2bf(tile[tc + 1][orow]);
    o[2] = f2bf(tile[tc + 2][orow]); o[3] = f2bf(tile[tc + 3][orow]);
    *(u16x4*)&O[(size_t)(c0 + orow) * EMB + r0 + tc] = o;
  }
}

// ---------------- GEMM core (128x128, 4 waves): used by gemm_out ----------------

static __device__ __forceinline__ void gemm_core(const u16* __restrict__ A, const u16* __restrict__ BT,
                                                 int m0, int n0, f32x4 acc[4][4]) {
  __shared__ u16 As[2][128 * 64];
  __shared__ u16 Bs[2][128 * 64];
  const int t = threadIdx.x, l = t & 63, w = t >> 6;
  const int g = l >> 4, q = l & 15;
  const int wm = (w >> 1) * 64, wn = (w & 1) * 64;

  const f32x4 zero4 = {0.f, 0.f, 0.f, 0.f};
#pragma unroll
  for (int mi = 0; mi < 4; mi++)
#pragma unroll
    for (int ni = 0; ni < 4; ni++) acc[mi][ni] = zero4;

  int srow[4], skel[4];
#pragma unroll
  for (int i = 0; i < 4; i++) {
    int row = w * 32 + i * 8 + (l >> 3);
    srow[i] = row; skel[i] = ((l & 7) ^ (row & 7)) * 8;
  }

  auto stage = [&](int k0, int bsel) {
    char* AsB = (char*)As[bsel] + w * 4096;
    char* BsB = (char*)Bs[bsel] + w * 4096;
#pragma unroll
    for (int i = 0; i < 4; i++) {
      gload16(A + (size_t)(m0 + srow[i]) * EMB + k0 + skel[i], AsB + i * 1024);
      gload16(BT + (size_t)(n0 + srow[i]) * EMB + k0 + skel[i], BsB + i * 1024);
    }
  };

  auto compute = [&](int bsel) {
    char* AsB = (char*)As[bsel];
    char* BsB = (char*)Bs[bsel];
#pragma unroll
    for (int kc = 0; kc < 2; kc++) {
      bf16x8 af[4], bfv[4];
#pragma unroll
      for (int mi = 0; mi < 4; mi++) {
        int row = wm + mi * 16 + q;
        af[mi] = *(const bf16x8*)(AsB + row * 128 + (((kc * 4 + g) ^ (row & 7)) << 4));
      }
#pragma unroll
      for (int ni = 0; ni < 4; ni++) {
        int row = wn + ni * 16 + q;
        bfv[ni] = *(const bf16x8*)(BsB + row * 128 + (((kc * 4 + g) ^ (row & 7)) << 4));
      }
      __builtin_amdgcn_s_setprio(1);
#pragma unroll
      for (int mi = 0; mi < 4; mi++)
#pragma unroll
        for (int ni = 0; ni < 4; ni++)
          acc[mi][ni] = __builtin_amdgcn_mfma_f32_16x16x32_bf16(af[mi], bfv[ni], acc[mi][ni], 0, 0, 0);
      __builtin_amdgcn_s_setprio(0);
    }
  };

  stage(0, 0);
  int buf = 0;
  for (int k0 = 64; k0 <= EMB; k0 += 64) {
    const bool pf = (k0 < EMB);
    if (pf) {
      stage(k0, buf ^ 1);
      asm volatile("s_waitcnt vmcnt(8)" ::: "memory");
    } else {
      asm volatile("s_waitcnt vmcnt(0)" ::: "memory");
    }
    __builtin_amdgcn_s_barrier();
    __builtin_amdgcn_sched_barrier(0);
    compute(buf);
    asm volatile("s_waitcnt lgkmcnt(0)" ::: "memory");
    __builtin_amdgcn_s_barrier();
    buf ^= 1;
  }
}

// ---------------- Fused QKV: 256x256 tile, 8 waves, 8-phase schedule ----------------
__global__ __launch_bounds__(512, 2) void k_gemm_qkv(const u16* __restrict__ xb, const u16* __restrict__ Wqkv,
                                                     u16* __restrict__ Qb, u16* __restrict__ Kb, u16* __restrict__ Vb) {
  __shared__ u16 As[2][256 * 64];   // 64 KB  [dbuf][row][k], rows 0-127 = half0, 128-255 = half1
  __shared__ u16 Bs[2][256 * 64];   // 64 KB
  const int t = threadIdx.x, l = t & 63, wid = t >> 6;
  const int g = l >> 4, q = l & 15;
  const int wr = wid >> 2, wc = wid & 3;        // 2 x 4 wave grid within quadrant

  const int wg = blockIdx.x;                    // 384 = 32 m x 12 n
  const int c = wg & 7, local = wg >> 3;        // XCD c gets n-outer chunk
  const int idx = c * 48 + local;
  const int ni_ = idx >> 5, mi_ = idx & 31;
  const int m0 = mi_ * 256, n0 = ni_ * 256;

  f32x4 acc[2][2][4][2];                        // [R][C][mi][ni]
  const f32x4 zero4 = {0.f, 0.f, 0.f, 0.f};
#pragma unroll
  for (int R = 0; R < 2; R++)
#pragma unroll
    for (int C = 0; C < 2; C++)
#pragma unroll
      for (int mi = 0; mi < 4; mi++)
#pragma unroll
        for (int ni = 0; ni < 2; ni++) acc[R][C][mi][ni] = zero4;

  int srow[2], skel[2];
#pragma unroll
  for (int j = 0; j < 2; j++) {
    int row = j * 64 + (t >> 3);
    srow[j] = row; skel[j] = ((t & 7) ^ (row & 7)) * 8;
  }

  auto stageHalf = [&](int op, int half, int tile) {
    if (tile >= 16) return;
    const int kk = tile * 64, d = tile & 1;
    const u16* src = op ? Wqkv : xb;
    const int base = op ? n0 : m0;
    char* dst = (char*)(op ? Bs[d] : As[d]) + half * 16384 + wid * 1024;
#pragma unroll
    for (int j = 0; j < 2; j++)
      gload16(src + (size_t)(base + half * 128 + srow[j]) * EMB + kk + skel[j], dst + j * 8192);
  };

  bf16x8 af[4][2], bf0[2][2], bf1[2][2];
  auto loadA = [&](int R, int d) {
    char* Ab = (char*)As[d];
#pragma unroll
    for (int mi = 0; mi < 4; mi++)
#pragma unroll
      for (int kc = 0; kc < 2; kc++) {
        int row = R * 128 + wr * 64 + mi * 16 + q;
        af[mi][kc] = *(const bf16x8*)(Ab + row * 128 + (((kc * 4 + g) ^ (row & 7)) << 4));
      }
  };
  auto loadB = [&](int C, int d, bf16x8 (&bfv)[2][2]) {
    char* Bb = (char*)Bs[d];
#pragma unroll
    for (int ni = 0; ni < 2; ni++)
#pragma unroll
      for (int kc = 0; kc < 2; kc++) {
        int row = C * 128 + wc * 32 + ni * 16 + q;
        bfv[ni][kc] = *(const bf16x8*)(Bb + row * 128 + (((kc * 4 + g) ^ (row & 7)) << 4));
      }
  };

#define MFMA16(R, C, BF)                                                                   \
  do {                                                                                     \
    __builtin_amdgcn_s_setprio(1);                                                         \
    _Pragma("unroll")                                                                      \
    for (int kc = 0; kc < 2; kc++)                                                         \
      _Pragma("unroll")                                                                    \
      for (int mi = 0; mi < 4; mi++)                                                       \
        _Pragma("unroll")                                                                  \
        for (int ni = 0; ni < 2; ni++)                                                     \
          acc[R][C][mi][ni] = __builtin_amdgcn_mfma_f32_16x16x32_bf16(af[mi][kc], BF[ni][kc], acc[R][C][mi][ni], 0, 0, 0); \
    __builtin_amdgcn_s_setprio(0);                                                         \
  } while (0)

  stageHalf(0, 0, 0); stageHalf(1, 0, 0); stageHalf(1, 1, 0); stageHalf(0, 1, 0);
  stageHalf(0, 0, 1); stageHalf(1, 1, 1);
  asm volatile("s_waitcnt vmcnt(4)" ::: "memory");
  __builtin_amdgcn_s_barrier();
  __builtin_amdgcn_sched_barrier(0);

  for (int kt = 0; kt < 16; ++kt) {
    const int d = kt & 1;
    loadA(0, d); loadB(0, d, bf0);
    stageHalf(0, 1, kt + 1);                 // A1(kt+1)
    __builtin_amdgcn_s_barrier();
    MFMA16(0, 0, bf0);
    __builtin_amdgcn_s_barrier();
    __builtin_amdgcn_sched_barrier(0);
    loadB(1, d, bf1);
    stageHalf(1, 0, kt + 1);                 // B0(kt+1)
    __builtin_amdgcn_s_barrier();
    MFMA16(0, 1, bf1);
    __builtin_amdgcn_s_barrier();
    __builtin_amdgcn_sched_barrier(0);
    loadA(1, d);
    stageHalf(0, 0, kt + 2);                 // A0(kt+2)
    __builtin_amdgcn_s_barrier();
    MFMA16(1, 1, bf1);
    __builtin_amdgcn_s_barrier();
    __builtin_amdgcn_sched_barrier(0);
    stageHalf(1, 1, kt + 2);                 // B1(kt+2)
    __builtin_amdgcn_s_barrier();
    MFMA16(1, 0, bf0);
    if (kt <= 13)      asm volatile("s_waitcnt vmcnt(4)" ::: "memory");
    else if (kt == 14) asm volatile("s_waitcnt vmcnt(0)" ::: "memory");
    __builtin_amdgcn_s_barrier();
    __builtin_amdgcn_sched_barrier(0);
  }
#undef MFMA16

  const int z = n0 >> 10;
  u16* Out = z == 0 ? Qb : (z == 1 ? Kb : Vb);
  const float scale = z == 0 ? 0.125f * 1.4426950408889634f : 1.0f;

#pragma unroll
  for (int R = 0; R < 2; R++)
#pragma unroll
    for (int C = 0; C < 2; C++)
#pragma unroll
      for (int mi = 0; mi < 4; mi++)
#pragma unroll
        for (int ni = 0; ni < 2; ni++)
#pragma unroll
          for (int jj = 0; jj < 4; jj++) {
            int m = m0 + R * 128 + wr * 64 + mi * 16 + g * 4 + jj;
            int n = n0 + C * 128 + wc * 32 + ni * 16 + q;
            int b = m >> 11, s = m & 2047;
            int col = n & 1023;
            int h = col >> 6, dd = col & 63;
            Out[(((size_t)(b * NHEAD + h)) * SEQ + s) * DHEAD + dd] = f2bf(acc[R][C][mi][ni][jj] * scale);
          }
}

// Output projection: out(fp32) = Ob * Wo + bo. 512 = 64 m x 8 n; XCD c owns n-panel c.
__global__ __launch_bounds__(256) void k_gemm_out(const u16* __restrict__ Ob, const u16* __restrict__ WoT,
                                                  const float* __restrict__ bo, float* __restrict__ out) {
  const int wg = blockIdx.x;
  const int c = wg & 7, local = wg >> 3;
  const int m0 = (local & 63) * 128, n0 = c * 128;

  f32x4 acc[4][4];
  gemm_core(Ob, WoT, m0, n0, acc);

  const int t = threadIdx.x, l = t & 63, w = t >> 6;
  const int g = l >> 4, q = l & 15;
  const int wm = (w >> 1) * 64, wn = (w & 1) * 64;
#pragma unroll
  for (int ni = 0; ni < 4; ni++) {
    int n = n0 + wn + ni * 16 + q;
    float bv = bo[n];
#pragma unroll
    for (int mi = 0; mi < 4; mi++)
#pragma unroll
      for (int jj = 0; jj < 4; jj++) {
        int m = m0 + wm + mi * 16 + g * 4 + jj;
        out[(size_t)m * EMB + n] = acc[mi][ni][jj] + bv;
      }
  }
}

// ---------------- causal flash attention (merged-pair, zero-shuffle P, per-stream frags) ----------------
// R12 configuration (best measured, confirmed x4): q-tile pair (i, 31-i) per block, 4 waves,
// per-stream ds_reads, P in registers via sigma V layout, VALU-lean softmax, deferred l
// reduction, K/V double-buffered + prefetched. VGPR 64 / LDS 32KB / zero conflicts / zero spill.
__global__ __launch_bounds__(256, 4) void k_attn(const u16* __restrict__ Qb, const u16* __restrict__ Kb,
                                                 const u16* __restrict__ Vb, u16* __restrict__ Ob) {
  __shared__ u16 Ks[2][64 * 64];    // [key][d], swizzled 16B chunks, natural key order
  __shared__ u16 Vt[2][64 * 64];    // [d][slot], swizzled 16B chunks, sigma slot order
  const int t = threadIdx.x, l = t & 63, w = t >> 6;
  const int g = l >> 4, q = l & 15;
  const int bh = blockIdx.x;
  const int b = bh >> 4, h = bh & 15;
  const size_t hb = (size_t)bh * SEQ * DHEAD;
  const float NEG_INF = -__builtin_inff();

  const int i = blockIdx.y;
  const int qA0 = i * 64, qB0 = (31 - i) * 64;
  const int ntA = i + 1, ntB = 32 - i;

  int krow[2], kel[2];
#pragma unroll
  for (int ii = 0; ii < 2; ii++) {
    int row = w * 16 + ii * 8 + (l >> 3);
    krow[ii] = row; kel[ii] = ((l & 7) ^ (row & 7)) * 8;
  }
  const int kp = t & 31, d0v = (t >> 5) * 8;
  const int r2 = 2 * kp;
  const int sp = 32 * ((r2 >> 4) >> 1) + 8 * ((r2 >> 2) & 3) + 4 * ((r2 >> 4) & 1) + (r2 & 3);

  // precomputed LDS byte offsets (identical formula for K-frag and V-frag reads)
  int olds[2][4], owv[8];
#pragma unroll
  for (int kc = 0; kc < 2; kc++)
#pragma unroll
    for (int kf = 0; kf < 4; kf++) {
      int row = kf * 16 + q;
      olds[kc][kf] = row * 128 + (((kc * 4 + g) ^ (row & 7)) << 4);
    }
#pragma unroll
  for (int ii = 0; ii < 8; ii++) {
    int d = d0v + ii;
    owv[ii] = d * 128 + ((sp * 2) ^ ((d & 7) << 4));
  }

  // running global pointers (advance 64 rows x 64 d = 4096 elems per k-tile)
  const u16* kgp0 = Kb + hb + (size_t)krow[0] * DHEAD + kel[0];
  const u16* kgp1 = Kb + hb + (size_t)krow[1] * DHEAD + kel[1];
  const u16* vgp0 = Vb + hb + (size_t)(2 * kp) * DHEAD + d0v;
  const u16* vgp1 = vgp0 + DHEAD;

  auto stageK = [&](const u16* p0, const u16* p1, int bsel) {
    char* dst = (char*)Ks[bsel] + w * 2048;
    gload16(p0, dst);
    gload16(p1, dst + 1024);
  };
  auto writeV = [&](int bsel, const u16x8& v0, const u16x8& v1) {
    char* VtB = (char*)Vt[bsel];
#pragma unroll
    for (int ii = 0; ii < 8; ii++) {
      u32 val = (u32)v0[ii] | ((u32)v1[ii] << 16);
      *(u32*)(VtB + owv[ii]) = val;
    }
  };

  bf16x8 qfA[2], qfB[2];
#pragma unroll
  for (int kc = 0; kc < 2; kc++) {
    qfA[kc] = *(const bf16x8*)(Qb + hb + (size_t)(qA0 + w * 16 + q) * DHEAD + kc * 32 + g * 8);
    qfB[kc] = *(const bf16x8*)(Qb + hb + (size_t)(qB0 + w * 16 + q) * DHEAD + kc * 32 + g * 8);
  }
  const int qglobA = qA0 + w * 16 + q, qglobB = qB0 + w * 16 + q;

  f32x4 oA[4], oB[4];
  const f32x4 zero4 = {0.f, 0.f, 0.f, 0.f};
#pragma unroll
  for (int df = 0; df < 4; df++) { oA[df] = zero4; oB[df] = zero4; }
  float mA = NEG_INF, lA = 0.f, mB = NEG_INF, lB = 0.f;

  auto compute = [&](const bf16x8 (&qf)[2], f32x4 (&o)[4], float& m_run, float& l_run,
                     bool diag, int qglob, int k0, const char* KsB, const char* VtB) {
    f32x4 st[4];
#pragma unroll
    for (int kf = 0; kf < 4; kf++) st[kf] = zero4;
    __builtin_amdgcn_s_setprio(1);
#pragma unroll
    for (int kc = 0; kc < 2; kc++)
#pragma unroll
      for (int kf = 0; kf < 4; kf++) {
        bf16x8 a = *(const bf16x8*)(KsB + olds[kc][kf]);
        st[kf] = __builtin_amdgcn_mfma_f32_16x16x32_bf16(a, qf[kc], st[kf], 0, 0, 0);
      }
    __builtin_amdgcn_s_setprio(0);

    if (diag) {
#pragma unroll
      for (int kf = 0; kf < 4; kf++)
#pragma unroll
        for (int jj = 0; jj < 4; jj++)
          if (k0 + kf * 16 + g * 4 + jj > qglob) st[kf][jj] = NEG_INF;
    }

    // max3-friendly 16->1 tree (clang fuses fmaxf(fmaxf(a,b),c) -> v_max3_f32)
    float x0 = fmaxf(fmaxf(st[0][0], st[0][1]), st[0][2]);
    float x1 = fmaxf(fmaxf(st[0][3], st[1][0]), st[1][1]);
    float x2 = fmaxf(fmaxf(st[1][2], st[1][3]), st[2][0]);
    float x3 = fmaxf(fmaxf(st[2][1], st[2][2]), st[2][3]);
    float x4 = fmaxf(fmaxf(st[3][0], st[3][1]), st[3][2]);
    float smax = fmaxf(fmaxf(x0, x1), x2);
    smax = fmaxf(fmaxf(smax, x3), x4);
    smax = fmaxf(smax, st[3][3]);
    smax = fmaxf(smax, __shfl_xor(smax, 16));
    smax = fmaxf(smax, __shfl_xor(smax, 32));

    if (!__all(smax - m_run <= 8.0f)) {   // defer-max (log2 domain)
      float mnew = fmaxf(m_run, smax);
      float sc = fexp2(m_run - mnew);
      l_run *= sc;                        // per-lane partial scales identically
#pragma unroll
      for (int jj = 0; jj < 4; jj++) {
        float scj = __shfl(sc, g * 4 + jj);
#pragma unroll
        for (int df = 0; df < 4; df++) o[df][jj] *= scj;
      }
      m_run = mnew;
    }

    f32x4 pv[4];
#pragma unroll
    for (int kf = 0; kf < 4; kf++)
#pragma unroll
      for (int jj = 0; jj < 4; jj++)
        pv[kf][jj] = fexp2(st[kf][jj] - m_run);
    f32x4 sv = (pv[0] + pv[1]) + (pv[2] + pv[3]);
    l_run += (sv[0] + sv[1]) + (sv[2] + sv[3]);   // per-lane partial; reduced at epilogue

    bf16x8 pa[2];
    pa[0] = bf16x8{ (__bf16)pv[0][0], (__bf16)pv[0][1], (__bf16)pv[0][2], (__bf16)pv[0][3],
                    (__bf16)pv[1][0], (__bf16)pv[1][1], (__bf16)pv[1][2], (__bf16)pv[1][3] };
    pa[1] = bf16x8{ (__bf16)pv[2][0], (__bf16)pv[2][1], (__bf16)pv[2][2], (__bf16)pv[2][3],
                    (__bf16)pv[3][0], (__bf16)pv[3][1], (__bf16)pv[3][2], (__bf16)pv[3][3] };

    __builtin_amdgcn_s_setprio(1);
#pragma unroll
    for (int kc = 0; kc < 2; kc++)
#pragma unroll
      for (int df = 0; df < 4; df++) {
        bf16x8 vb = *(const bf16x8*)(VtB + olds[kc][df]);
        o[df] = __builtin_amdgcn_mfma_f32_16x16x32_bf16(pa[kc], vb, o[df], 0, 0, 0);
      }
    __builtin_amdgcn_s_setprio(0);
  };

  {  // prologue: stage tile 0
    u16x8 v0 = *(const u16x8*)vgp0, v1 = *(const u16x8*)vgp1;
    stageK(kgp0, kgp1, 0);
    writeV(0, v0, v1);
    kgp0 += 4096; kgp1 += 4096; vgp0 += 4096; vgp1 += 4096;
  }
  __syncthreads();

  int buf = 0;
  for (int kt = 0; kt < ntB; ++kt) {
    const int k0 = kt * 64;
    const bool pf = (kt + 1 < ntB);
    u16x8 nv0, nv1;
    if (pf) {
      stageK(kgp0, kgp1, buf ^ 1);
      nv0 = *(const u16x8*)vgp0; nv1 = *(const u16x8*)vgp1;
      kgp0 += 4096; kgp1 += 4096; vgp0 += 4096; vgp1 += 4096;
    }
    const char* KsB = (const char*)Ks[buf];
    const char* VtB = (const char*)Vt[buf];

    compute(qfB, oB, mB, lB, kt == ntB - 1, qglobB, k0, KsB, VtB);
    if (kt < ntA)
      compute(qfA, oA, mA, lA, kt == ntA - 1, qglobA, k0, KsB, VtB);

    if (pf) writeV(buf ^ 1, nv0, nv1);
    __syncthreads();
    buf ^= 1;
  }

  // epilogue: finish deferred l reduction, normalize, store (B,S,E) bf16
  lA += __shfl_xor(lA, 16); lA += __shfl_xor(lA, 32);
  lB += __shfl_xor(lB, 16); lB += __shfl_xor(lB, 32);

  auto store = [&](f32x4 (&o)[4], float l_run, int q0) {
    float inv = 1.f / l_run;
#pragma unroll
    for (int jj = 0; jj < 4; jj++) {
      float r = __shfl(inv, g * 4 + jj);
      int s = q0 + w * 16 + g * 4 + jj;
#pragma unroll
      for (int df = 0; df < 4; df++)
        Ob[((size_t)(b * SEQ + s)) * EMB + h * DHEAD + df * 16 + q] = f2bf(o[df][jj] * r);
    }
  };
  store(oA, lA, qA0);
  store(oB, lB, qB0);
}

// ---------------- host ----------------

extern "C" void kernel_launch(void* const* d_in, const int* in_sizes, int n_in,
                              void* d_out, int out_size, void* d_ws, size_t ws_size,
                              hipStream_t stream) {
  const float* x  = (const float*)d_in[0];
  const float* Wq = (const float*)d_in[1];
  const float* Wk = (const float*)d_in[2];
  const float* Wv = (const float*)d_in[3];
  const float* Wo = (const float*)d_in[4];
  const float* bo = (const float*)d_in[5];
  float* out = (float*)d_out;

  char* ws = (char*)d_ws;
  u16* xb  = (u16*)(ws);                                   // 16 MB
  u16* WqT = (u16*)(ws + (16u << 20));                     // 2 MB each; Wq/Wk/Wv contiguous = fused B
  u16* WkT = WqT + (size_t)EMB * EMB;
  u16* WvT = WkT + (size_t)EMB * EMB;
  u16* WoT = WvT + (size_t)EMB * EMB;
  u16* Qb  = (u16*)(ws + (24u << 20));                     // 16 MB each
  u16* Kb  = Qb + (size_t)MTOT * EMB;
  u16* Vb  = Kb + (size_t)MTOT * EMB;
  u16* Ob  = Vb + (size_t)MTOT * EMB;                      // total 88 MB

  k_prep<<<dim3(5120), 256, 0, stream>>>(x, xb, Wq, Wk, Wv, Wo, WqT, WkT, WvT, WoT);
  k_gemm_qkv<<<dim3(384), 512, 0, stream>>>(xb, WqT, Qb, Kb, Vb);
  k_attn<<<dim3(64, 16), 256, 0, stream>>>(Qb, Kb, Vb, Ob);
  k_gemm_out<<<dim3(512), 256, 0, stream>>>(Ob, WoT, bo, out);
}